// Round 1
// baseline (460.754 us; speedup 1.0000x reference)
//
#include <hip/hip_runtime.h>
#include <hip/hip_bf16.h>

typedef __attribute__((ext_vector_type(8))) __bf16 bf16x8;
typedef __attribute__((ext_vector_type(4))) float f32x4;

#define HID 1024      // H
#define FD  768       // F (K of first GEMM)
#define MR  8192      // B*E == B*D rows
#define BM  128
#define BN  128
#define BK  32
#define KSTEPS (FD / BK)   // 24
#define LSTR 40            // LDS row stride in bf16 elems (BK + 8 pad)

// ---------------------------------------------------------------------------
// Fused: s = relu(X @ W^T + b) * mask ; proj[row][c] += sum_h s[row][h]*W1[c][w1off+h]
// z=0: encoder (proj_e, w1off=H), z=1: decoder (proj_d, w1off=0)
// ---------------------------------------------------------------------------
__global__ __launch_bounds__(256)
void gemm_proj_kernel(const float* __restrict__ Xe, const float* __restrict__ Xd,
                      const float* __restrict__ me, const float* __restrict__ md,
                      const float* __restrict__ We, const float* __restrict__ be,
                      const float* __restrict__ Wd, const float* __restrict__ bd,
                      const float* __restrict__ W1,
                      float* __restrict__ pe, float* __restrict__ pd)
{
    const int z = blockIdx.z;
    const float* __restrict__ X    = z ? Xd : Xe;
    const float* __restrict__ Wt   = z ? Wd : We;
    const float* __restrict__ bias = z ? bd : be;
    const float* __restrict__ msk  = z ? md : me;
    float* __restrict__ proj       = z ? pd : pe;
    const int w1off = z ? 0 : HID;

    __shared__ __bf16 As[BM][LSTR];
    __shared__ __bf16 Bs[BN][LSTR];

    const int t    = threadIdx.x;
    const int lane = t & 63;
    const int wid  = t >> 6;
    const int wr   = wid >> 1;      // wave row (0..1)
    const int wc   = wid & 1;       // wave col (0..1)
    const int l15  = lane & 15;
    const int l4   = lane >> 4;

    const long m0 = (long)blockIdx.x * BM;
    const int  n0 = blockIdx.y * BN;

    f32x4 acc[4][4];
    #pragma unroll
    for (int i = 0; i < 4; ++i)
        #pragma unroll
        for (int j = 0; j < 4; ++j)
            acc[i][j] = (f32x4){0.f, 0.f, 0.f, 0.f};

    // staging: threads 0..127 stage A (one 32-f32 row each), 128..255 stage B
    const int srow = t & 127;
    const float* gsrc = (t >= 128) ? (Wt + (long)(n0 + srow) * FD)
                                   : (X  + (m0 + srow) * FD);
    __bf16* ldst = (t >= 128) ? &Bs[srow][0] : &As[srow][0];

    for (int ks = 0; ks < KSTEPS; ++ks) {
        const float4* gp = reinterpret_cast<const float4*>(gsrc + ks * BK);
        float4 v[8];
        #pragma unroll
        for (int j = 0; j < 8; ++j) v[j] = gp[j];

        __syncthreads();   // previous iteration's ds_reads complete

        #pragma unroll
        for (int j = 0; j < 4; ++j) {
            bf16x8 w;
            w[0] = (__bf16)v[2*j].x;   w[1] = (__bf16)v[2*j].y;
            w[2] = (__bf16)v[2*j].z;   w[3] = (__bf16)v[2*j].w;
            w[4] = (__bf16)v[2*j+1].x; w[5] = (__bf16)v[2*j+1].y;
            w[6] = (__bf16)v[2*j+1].z; w[7] = (__bf16)v[2*j+1].w;
            *reinterpret_cast<bf16x8*>(ldst + j * 8) = w;
        }
        __syncthreads();   // tile visible

        bf16x8 af[4], bfr[4];
        #pragma unroll
        for (int m = 0; m < 4; ++m)
            af[m] = *reinterpret_cast<const bf16x8*>(&As[wr*64 + m*16 + l15][l4*8]);
        #pragma unroll
        for (int n = 0; n < 4; ++n)
            bfr[n] = *reinterpret_cast<const bf16x8*>(&Bs[wc*64 + n*16 + l15][l4*8]);

        #pragma unroll
        for (int m = 0; m < 4; ++m)
            #pragma unroll
            for (int n = 0; n < 4; ++n)
                acc[m][n] = __builtin_amdgcn_mfma_f32_16x16x32_bf16(
                                af[m], bfr[n], acc[m][n], 0, 0, 0);
    }

    // epilogue: bias + relu + mask, project onto 3 W1 rows, reduce over lanes
    float bh[4], w1c0[4], w1c1[4], w1c2[4];
    #pragma unroll
    for (int n = 0; n < 4; ++n) {
        int h = n0 + wc*64 + n*16 + l15;
        bh[n]   = bias[h];
        w1c0[n] = W1[0*2*HID + w1off + h];
        w1c1[n] = W1[1*2*HID + w1off + h];
        w1c2[n] = W1[2*2*HID + w1off + h];
    }

    #pragma unroll
    for (int m = 0; m < 4; ++m) {
        #pragma unroll
        for (int r = 0; r < 4; ++r) {
            long row = m0 + wr*64 + m*16 + l4*4 + r;
            float mk = msk[row];
            float p0 = 0.f, p1 = 0.f, p2 = 0.f;
            #pragma unroll
            for (int n = 0; n < 4; ++n) {
                float s = acc[m][n][r] + bh[n];
                s = fmaxf(s, 0.f) * mk;
                p0 = fmaf(s, w1c0[n], p0);
                p1 = fmaf(s, w1c1[n], p1);
                p2 = fmaf(s, w1c2[n], p2);
            }
            #pragma unroll
            for (int off = 1; off < 16; off <<= 1) {
                p0 += __shfl_xor(p0, off);
                p1 += __shfl_xor(p1, off);
                p2 += __shfl_xor(p2, off);
            }
            if (l15 == 0) {
                atomicAdd(&proj[row*3+0], p0);
                atomicAdd(&proj[row*3+1], p1);
                atomicAdd(&proj[row*3+2], p2);
            }
        }
    }
}

// ---------------------------------------------------------------------------
// loss: one block per (b,d); 256 threads x 4 e-points each
// ---------------------------------------------------------------------------
__global__ __launch_bounds__(256)
void loss_kernel(const float* __restrict__ pe, const float* __restrict__ pd,
                 const float* __restrict__ b1, const int* __restrict__ labels,
                 float* __restrict__ accv)
{
    const int bd = blockIdx.x;          // b*1024 + d
    const int b  = bd >> 10;
    const int t  = threadIdx.x;

    const float d0 = pd[bd*3+0] + b1[0];
    const float d1 = pd[bd*3+1] + b1[1];
    const float d2 = pd[bd*3+2] + b1[2];

    const int e0 = t * 4;
    const float4* pep = reinterpret_cast<const float4*>(pe + ((long)b*1024 + e0)*3);
    float4 q0 = pep[0], q1 = pep[1], q2 = pep[2];
    const int4 lb = *reinterpret_cast<const int4*>(labels + (long)bd*1024 + e0);

    float epv[12] = {q0.x,q0.y,q0.z,q0.w, q1.x,q1.y,q1.z,q1.w, q2.x,q2.y,q2.z,q2.w};
    int   lv[4]   = {lb.x, lb.y, lb.z, lb.w};

    float lsum = 0.f, lcnt = 0.f;
    #pragma unroll
    for (int i = 0; i < 4; ++i) {
        float l0 = d0 + epv[i*3+0];
        float l1 = d1 + epv[i*3+1];
        float l2 = d2 + epv[i*3+2];
        float mx  = fmaxf(l0, fmaxf(l1, l2));
        float lse = mx + logf(expf(l0-mx) + expf(l1-mx) + expf(l2-mx));
        int la = lv[i];
        if (la != -100) {
            float sel = (la == 0) ? l0 : ((la == 1) ? l1 : l2);
            lsum += lse - sel;
            lcnt += 1.f;
        }
    }
    #pragma unroll
    for (int off = 1; off < 64; off <<= 1) {
        lsum += __shfl_xor(lsum, off);
        lcnt += __shfl_xor(lcnt, off);
    }
    __shared__ float shs[4], shc[4];
    const int wid = t >> 6;
    if ((t & 63) == 0) { shs[wid] = lsum; shc[wid] = lcnt; }
    __syncthreads();
    if (t == 0) {
        atomicAdd(&accv[0], shs[0]+shs[1]+shs[2]+shs[3]);
        atomicAdd(&accv[1], shc[0]+shc[1]+shc[2]+shc[3]);
    }
}

__global__ void finalize_kernel(const float* __restrict__ accv, float* __restrict__ out)
{
    out[0] = accv[0] / fmaxf(accv[1], 1.0f);
}

// ---------------------------------------------------------------------------
extern "C" void kernel_launch(void* const* d_in, const int* in_sizes, int n_in,
                              void* d_out, int out_size, void* d_ws, size_t ws_size,
                              hipStream_t stream)
{
    (void)in_sizes; (void)n_in; (void)out_size; (void)ws_size;

    const float* enc   = (const float*)d_in[0];
    const float* dec   = (const float*)d_in[1];   // leading dim 1 -> [-1] is the base ptr
    const float* maske = (const float*)d_in[2];
    const float* maskd = (const float*)d_in[3];
    const float* We    = (const float*)d_in[4];
    const float* be    = (const float*)d_in[5];
    const float* Wd    = (const float*)d_in[6];
    const float* bd    = (const float*)d_in[7];
    const float* W1    = (const float*)d_in[8];
    const float* b1    = (const float*)d_in[9];
    const int*   labels= (const int*)d_in[10];

    float* pe   = (float*)d_ws;         // 8192*3
    float* pd   = pe + MR*3;            // 8192*3
    float* accv = pd + MR*3;            // [sum, count]

    hipMemsetAsync(d_ws, 0, (size_t)(2*MR*3 + 2) * sizeof(float), stream);

    dim3 grid(MR/BM, HID/BN, 2);
    gemm_proj_kernel<<<grid, 256, 0, stream>>>(enc, dec, maske, maskd,
                                               We, be, Wd, bd, W1, pe, pd);
    loss_kernel<<<MR, 256, 0, stream>>>(pe, pd, b1, labels, accv);
    finalize_kernel<<<1, 1, 0, stream>>>(accv, (float*)d_out);
}

// Round 2
// 236.112 us; speedup vs baseline: 1.9514x; 1.9514x over previous
//
#include <hip/hip_runtime.h>
#include <hip/hip_bf16.h>

typedef __attribute__((ext_vector_type(8))) __bf16 bf16x8;
typedef __attribute__((ext_vector_type(4))) float f32x4;

#define HID 1024      // H
#define FD  768       // F (K of first GEMM)
#define MR  8192      // B*E == B*D rows
#define BM  128
#define BN  128
#define BK  32
#define KSTEPS (FD / BK)   // 24

#define GLOAD_LDS16(g, l)                                                  \
    __builtin_amdgcn_global_load_lds(                                      \
        (const __attribute__((address_space(1))) unsigned int*)(g),        \
        (__attribute__((address_space(3))) unsigned int*)(l), 16, 0, 0)

// ---------------------------------------------------------------------------
// f32 -> bf16 conversion pass (Xe, Xd, We, Wd), 8 elems/thread
// segments: [0,3072) Xe  [3072,6144) Xd  [6144,6528) We  [6528,6912) Wd
// ---------------------------------------------------------------------------
__global__ __launch_bounds__(256)
void cvt_kernel(const float* __restrict__ se, const float* __restrict__ sd,
                const float* __restrict__ swe, const float* __restrict__ swd,
                __bf16* __restrict__ de, __bf16* __restrict__ dd,
                __bf16* __restrict__ dwe, __bf16* __restrict__ dwd)
{
    const int blk = blockIdx.x;
    const float* __restrict__ src;
    __bf16* __restrict__ dst;
    long base;
    if (blk < 3072)      { src = se;  dst = de;  base = (long)blk * 2048; }
    else if (blk < 6144) { src = sd;  dst = dd;  base = (long)(blk - 3072) * 2048; }
    else if (blk < 6528) { src = swe; dst = dwe; base = (long)(blk - 6144) * 2048; }
    else                 { src = swd; dst = dwd; base = (long)(blk - 6528) * 2048; }
    const long i = base + (long)threadIdx.x * 8;
    const float4 a = *reinterpret_cast<const float4*>(src + i);
    const float4 b = *reinterpret_cast<const float4*>(src + i + 4);
    bf16x8 w;
    w[0] = (__bf16)a.x; w[1] = (__bf16)a.y; w[2] = (__bf16)a.z; w[3] = (__bf16)a.w;
    w[4] = (__bf16)b.x; w[5] = (__bf16)b.y; w[6] = (__bf16)b.z; w[7] = (__bf16)b.w;
    *reinterpret_cast<bf16x8*>(dst + i) = w;
}

// ---------------------------------------------------------------------------
// Fused: s = relu(Xb @ Wb^T + b) * mask ; proj[row][c] += sum_h s*W1[c][w1off+h]
// m97 structure: global_load_lds width-16 into linear LDS, 2 barriers/K-step
// ---------------------------------------------------------------------------
__global__ __launch_bounds__(256)
void gemm_proj_kernel(const __bf16* __restrict__ Xe, const __bf16* __restrict__ Xd,
                      const __bf16* __restrict__ We, const __bf16* __restrict__ Wd,
                      const float* __restrict__ me, const float* __restrict__ md,
                      const float* __restrict__ be, const float* __restrict__ bd,
                      const float* __restrict__ W1,
                      float* __restrict__ pe, float* __restrict__ pd)
{
    const int z = blockIdx.z;
    const __bf16* __restrict__ X    = z ? Xd : Xe;
    const __bf16* __restrict__ Wt   = z ? Wd : We;
    const float* __restrict__ bias  = z ? bd : be;
    const float* __restrict__ msk   = z ? md : me;
    float* __restrict__ proj        = z ? pd : pe;
    const int w1off = z ? 0 : HID;

    __shared__ __bf16 As[BM][BK];   // 8 KB, linear (global_load_lds dest)
    __shared__ __bf16 Bs[BN][BK];   // 8 KB

    const int t    = threadIdx.x;
    const int lane = t & 63;
    const int wid  = t >> 6;
    const int wr   = wid >> 1;
    const int wc   = wid & 1;
    const int l15  = lane & 15;
    const int l4   = lane >> 4;

    const long m0 = (long)blockIdx.x * BM;
    const int  n0 = blockIdx.y * BN;

    f32x4 acc[4][4];
    #pragma unroll
    for (int i = 0; i < 4; ++i)
        #pragma unroll
        for (int j = 0; j < 4; ++j)
            acc[i][j] = (f32x4){0.f, 0.f, 0.f, 0.f};

    // staging geometry: wave wid stages rows [wid*32, wid*32+32) of A and B.
    // issue j covers 16 rows; lane l -> row l>>2, 16B chunk l&3.
    const int srow = lane >> 2;
    const int scol = (lane & 3) * 8;           // bf16 elems
    const __bf16* ga = X  + (m0 + wid*32 + srow) * (long)FD + scol;
    const __bf16* gb = Wt + (long)(n0 + wid*32 + srow) * FD + scol;

    for (int ks = 0; ks < KSTEPS; ++ks) {
        const int k0 = ks * BK;
        #pragma unroll
        for (int j = 0; j < 2; ++j) {
            GLOAD_LDS16(ga + (long)j*16*FD + k0, &As[wid*32 + j*16][0]);
            GLOAD_LDS16(gb + (long)j*16*FD + k0, &Bs[wid*32 + j*16][0]);
        }
        __syncthreads();   // vmcnt drain + barrier: tile visible

        bf16x8 af[4], bfr[4];
        #pragma unroll
        for (int m = 0; m < 4; ++m)
            af[m] = *reinterpret_cast<const bf16x8*>(&As[wr*64 + m*16 + l15][l4*8]);
        #pragma unroll
        for (int n = 0; n < 4; ++n)
            bfr[n] = *reinterpret_cast<const bf16x8*>(&Bs[wc*64 + n*16 + l15][l4*8]);

        #pragma unroll
        for (int m = 0; m < 4; ++m)
            #pragma unroll
            for (int n = 0; n < 4; ++n)
                acc[m][n] = __builtin_amdgcn_mfma_f32_16x16x32_bf16(
                                af[m], bfr[n], acc[m][n], 0, 0, 0);

        __syncthreads();   // ds_reads done before next stage overwrites
    }

    // epilogue: bias + relu + mask, project onto 3 W1 rows, reduce over 16 lanes
    float bh[4], w1c0[4], w1c1[4], w1c2[4];
    #pragma unroll
    for (int n = 0; n < 4; ++n) {
        int h = n0 + wc*64 + n*16 + l15;
        bh[n]   = bias[h];
        w1c0[n] = W1[0*2*HID + w1off + h];
        w1c1[n] = W1[1*2*HID + w1off + h];
        w1c2[n] = W1[2*2*HID + w1off + h];
    }

    #pragma unroll
    for (int m = 0; m < 4; ++m) {
        #pragma unroll
        for (int r = 0; r < 4; ++r) {
            long row = m0 + wr*64 + m*16 + l4*4 + r;
            float mk = msk[row];
            float p0 = 0.f, p1 = 0.f, p2 = 0.f;
            #pragma unroll
            for (int n = 0; n < 4; ++n) {
                float s = acc[m][n][r] + bh[n];
                s = fmaxf(s, 0.f) * mk;
                p0 = fmaf(s, w1c0[n], p0);
                p1 = fmaf(s, w1c1[n], p1);
                p2 = fmaf(s, w1c2[n], p2);
            }
            #pragma unroll
            for (int off = 1; off < 16; off <<= 1) {
                p0 += __shfl_xor(p0, off);
                p1 += __shfl_xor(p1, off);
                p2 += __shfl_xor(p2, off);
            }
            if (l15 == 0) {
                atomicAdd(&proj[row*3+0], p0);
                atomicAdd(&proj[row*3+1], p1);
                atomicAdd(&proj[row*3+2], p2);
            }
        }
    }
}

// ---------------------------------------------------------------------------
// loss: one block per (b,d); writes per-block partials (no global atomics)
// ---------------------------------------------------------------------------
__global__ __launch_bounds__(256)
void loss_kernel(const float* __restrict__ pe, const float* __restrict__ pd,
                 const float* __restrict__ b1, const int* __restrict__ labels,
                 float* __restrict__ psum, float* __restrict__ pcnt)
{
    const int bd = blockIdx.x;          // b*1024 + d
    const int b  = bd >> 10;
    const int t  = threadIdx.x;

    const float d0 = pd[bd*3+0] + b1[0];
    const float d1 = pd[bd*3+1] + b1[1];
    const float d2 = pd[bd*3+2] + b1[2];

    const int e0 = t * 4;
    const float4* pep = reinterpret_cast<const float4*>(pe + ((long)b*1024 + e0)*3);
    float4 q0 = pep[0], q1 = pep[1], q2 = pep[2];
    const int4 lb = *reinterpret_cast<const int4*>(labels + (long)bd*1024 + e0);

    float epv[12] = {q0.x,q0.y,q0.z,q0.w, q1.x,q1.y,q1.z,q1.w, q2.x,q2.y,q2.z,q2.w};
    int   lv[4]   = {lb.x, lb.y, lb.z, lb.w};

    float lsum = 0.f, lcnt = 0.f;
    #pragma unroll
    for (int i = 0; i < 4; ++i) {
        float l0 = d0 + epv[i*3+0];
        float l1 = d1 + epv[i*3+1];
        float l2 = d2 + epv[i*3+2];
        float mx  = fmaxf(l0, fmaxf(l1, l2));
        float lse = mx + __logf(__expf(l0-mx) + __expf(l1-mx) + __expf(l2-mx));
        int la = lv[i];
        if (la != -100) {
            float sel = (la == 0) ? l0 : ((la == 1) ? l1 : l2);
            lsum += lse - sel;
            lcnt += 1.f;
        }
    }
    #pragma unroll
    for (int off = 1; off < 64; off <<= 1) {
        lsum += __shfl_xor(lsum, off);
        lcnt += __shfl_xor(lcnt, off);
    }
    __shared__ float shs[4], shc[4];
    const int wid = t >> 6;
    if ((t & 63) == 0) { shs[wid] = lsum; shc[wid] = lcnt; }
    __syncthreads();
    if (t == 0) {
        psum[bd] = shs[0]+shs[1]+shs[2]+shs[3];
        pcnt[bd] = shc[0]+shc[1]+shc[2]+shc[3];
    }
}

__global__ __launch_bounds__(256)
void finalize_kernel(const float* __restrict__ psum, const float* __restrict__ pcnt,
                     float* __restrict__ out)
{
    const int t = threadIdx.x;
    float s = 0.f, c = 0.f;
    for (int i = t; i < MR; i += 256) { s += psum[i]; c += pcnt[i]; }
    #pragma unroll
    for (int off = 1; off < 64; off <<= 1) {
        s += __shfl_xor(s, off);
        c += __shfl_xor(c, off);
    }
    __shared__ float shs[4], shc[4];
    const int wid = t >> 6;
    if ((t & 63) == 0) { shs[wid] = s; shc[wid] = c; }
    __syncthreads();
    if (t == 0)
        out[0] = (shs[0]+shs[1]+shs[2]+shs[3]) / fmaxf(shc[0]+shc[1]+shc[2]+shc[3], 1.0f);
}

// ---------------------------------------------------------------------------
extern "C" void kernel_launch(void* const* d_in, const int* in_sizes, int n_in,
                              void* d_out, int out_size, void* d_ws, size_t ws_size,
                              hipStream_t stream)
{
    (void)in_sizes; (void)n_in; (void)out_size; (void)ws_size;

    const float* enc   = (const float*)d_in[0];
    const float* dec   = (const float*)d_in[1];   // (1,B,D,F) -> base ptr
    const float* maske = (const float*)d_in[2];
    const float* maskd = (const float*)d_in[3];
    const float* We    = (const float*)d_in[4];
    const float* be    = (const float*)d_in[5];
    const float* Wd    = (const float*)d_in[6];
    const float* bd    = (const float*)d_in[7];
    const float* W1    = (const float*)d_in[8];
    const float* b1    = (const float*)d_in[9];
    const int*   labels= (const int*)d_in[10];

    // ws layout (floats first, then bf16 buffers)
    float* pe   = (float*)d_ws;                   // 3*MR
    float* pd   = pe + 3*MR;                      // 3*MR
    float* psum = pd + 3*MR;                      // MR
    float* pcnt = psum + MR;                      // MR
    __bf16* Xeb = (__bf16*)(pcnt + MR);           // MR*FD
    __bf16* Xdb = Xeb + (long)MR*FD;              // MR*FD
    __bf16* Web = Xdb + (long)MR*FD;              // HID*FD
    __bf16* Wdb = Web + (long)HID*FD;             // HID*FD

    hipMemsetAsync(d_ws, 0, (size_t)(6*MR) * sizeof(float), stream);

    cvt_kernel<<<6912, 256, 0, stream>>>(enc, dec, We, Wd, Xeb, Xdb, Web, Wdb);

    dim3 grid(MR/BM, HID/BN, 2);
    gemm_proj_kernel<<<grid, 256, 0, stream>>>(Xeb, Xdb, Web, Wdb,
                                               maske, maskd, be, bd, W1, pe, pd);
    loss_kernel<<<MR, 256, 0, stream>>>(pe, pd, b1, labels, psum, pcnt);
    finalize_kernel<<<1, 256, 0, stream>>>(psum, pcnt, (float*)d_out);
}

// Round 3
// 182.625 us; speedup vs baseline: 2.5230x; 1.2929x over previous
//
#include <hip/hip_runtime.h>
#include <hip/hip_bf16.h>

typedef __attribute__((ext_vector_type(8))) __bf16 bf16x8;
typedef __attribute__((ext_vector_type(4))) float f32x4;

#define HID 1024      // H
#define FD  768       // F (K of first GEMM)
#define MR  8192      // B*E == B*D rows
#define BM  128
#define BN  128
#define BK  32
#define KSTEPS (FD / BK)   // 24

#define GLOAD_LDS16(g, l)                                                  \
    __builtin_amdgcn_global_load_lds(                                      \
        (const __attribute__((address_space(1))) unsigned int*)(g),        \
        (__attribute__((address_space(3))) unsigned int*)(l), 16, 0, 0)

// ---------------------------------------------------------------------------
// f32 -> bf16 conversion pass (Xe, Xd, We, Wd), 8 elems/thread
// ---------------------------------------------------------------------------
__global__ __launch_bounds__(256)
void cvt_kernel(const float* __restrict__ se, const float* __restrict__ sd,
                const float* __restrict__ swe, const float* __restrict__ swd,
                __bf16* __restrict__ de, __bf16* __restrict__ dd,
                __bf16* __restrict__ dwe, __bf16* __restrict__ dwd)
{
    const int blk = blockIdx.x;
    const float* __restrict__ src;
    __bf16* __restrict__ dst;
    long base;
    if (blk < 3072)      { src = se;  dst = de;  base = (long)blk * 2048; }
    else if (blk < 6144) { src = sd;  dst = dd;  base = (long)(blk - 3072) * 2048; }
    else if (blk < 6528) { src = swe; dst = dwe; base = (long)(blk - 6144) * 2048; }
    else                 { src = swd; dst = dwd; base = (long)(blk - 6528) * 2048; }
    const long i = base + (long)threadIdx.x * 8;
    const float4 a = *reinterpret_cast<const float4*>(src + i);
    const float4 b = *reinterpret_cast<const float4*>(src + i + 4);
    bf16x8 w;
    w[0] = (__bf16)a.x; w[1] = (__bf16)a.y; w[2] = (__bf16)a.z; w[3] = (__bf16)a.w;
    w[4] = (__bf16)b.x; w[5] = (__bf16)b.y; w[6] = (__bf16)b.z; w[7] = (__bf16)b.w;
    *reinterpret_cast<bf16x8*>(dst + i) = w;
}

// ---------------------------------------------------------------------------
// Fused: s = relu(Xb @ Wb^T + b) ; proj[row][c] += mask[row]*sum_h s*W1[c][w1off+h]
// T3-minimum pipeline: double-buffered LDS, prefetch STAGE before compute,
// ONE barrier per K-step. Epilogue: two-pass LDS reduction (union over staging).
// ---------------------------------------------------------------------------
__global__ __launch_bounds__(256)
void gemm_proj_kernel(const __bf16* __restrict__ Xe, const __bf16* __restrict__ Xd,
                      const __bf16* __restrict__ We, const __bf16* __restrict__ Wd,
                      const float* __restrict__ me, const float* __restrict__ md,
                      const float* __restrict__ be, const float* __restrict__ bd,
                      const float* __restrict__ W1,
                      float* __restrict__ pe, float* __restrict__ pd)
{
    const int z = blockIdx.z;
    const __bf16* __restrict__ X    = z ? Xd : Xe;
    const __bf16* __restrict__ Wt   = z ? Wd : We;
    const float* __restrict__ bias  = z ? bd : be;
    const float* __restrict__ msk   = z ? md : me;
    float* __restrict__ proj        = z ? pd : pe;
    const int w1off = z ? 0 : HID;

    __shared__ union {
        struct { __bf16 A[2][BM][BK]; __bf16 B[2][BN][BK]; } st;  // 32 KB
        f32x4 red[BM][16];                                        // 32 KB
    } sm;

    const int t    = threadIdx.x;
    const int lane = t & 63;
    const int wid  = t >> 6;
    const int wr   = wid >> 1;
    const int wc   = wid & 1;
    const int l15  = lane & 15;
    const int l4   = lane >> 4;

    const long m0 = (long)blockIdx.x * BM;
    const int  n0 = blockIdx.y * BN;

    f32x4 acc[4][4];
    #pragma unroll
    for (int i = 0; i < 4; ++i)
        #pragma unroll
        for (int j = 0; j < 4; ++j)
            acc[i][j] = (f32x4){0.f, 0.f, 0.f, 0.f};

    // staging geometry: wave wid stages rows [wid*32, wid*32+32) of A and B.
    // one issue covers 16 rows (1024 B linear); lane l -> row l>>2, 16B chunk l&3
    const int srow = lane >> 2;
    const int scol = (lane & 3) * 8;
    const __bf16* ga = X  + (m0 + wid*32 + srow) * (long)FD + scol;
    const __bf16* gb = Wt + (long)(n0 + wid*32 + srow) * FD + scol;

#define STAGE(p, ks) do {                                                  \
        const int k0_ = (ks) * BK;                                         \
        GLOAD_LDS16(ga + k0_,               &sm.st.A[p][wid*32 +  0][0]);  \
        GLOAD_LDS16(ga + (long)16*FD + k0_, &sm.st.A[p][wid*32 + 16][0]);  \
        GLOAD_LDS16(gb + k0_,               &sm.st.B[p][wid*32 +  0][0]);  \
        GLOAD_LDS16(gb + (long)16*FD + k0_, &sm.st.B[p][wid*32 + 16][0]);  \
    } while (0)

    STAGE(0, 0);
    __syncthreads();

    int cur = 0;
    for (int ks = 0; ks < KSTEPS; ++ks) {
        if (ks + 1 < KSTEPS) STAGE(cur ^ 1, ks + 1);   // prefetch next tile

        bf16x8 af[4], bfr[4];
        #pragma unroll
        for (int m = 0; m < 4; ++m)
            af[m] = *reinterpret_cast<const bf16x8*>(&sm.st.A[cur][wr*64 + m*16 + l15][l4*8]);
        #pragma unroll
        for (int n = 0; n < 4; ++n)
            bfr[n] = *reinterpret_cast<const bf16x8*>(&sm.st.B[cur][wc*64 + n*16 + l15][l4*8]);

        #pragma unroll
        for (int m = 0; m < 4; ++m)
            #pragma unroll
            for (int n = 0; n < 4; ++n)
                acc[m][n] = __builtin_amdgcn_mfma_f32_16x16x32_bf16(
                                af[m], bfr[n], acc[m][n], 0, 0, 0);

        __syncthreads();   // drains vmcnt (stage landed) + lgkm; buffers swap-safe
        cur ^= 1;
    }

    // ---- epilogue: bias+relu, dot 3 W1 rows, two-pass LDS accumulate ----
    float bh[4], w1c0[4], w1c1[4], w1c2[4];
    #pragma unroll
    for (int n = 0; n < 4; ++n) {
        int h = n0 + wc*64 + n*16 + l15;
        bh[n]   = bias[h];
        w1c0[n] = W1[0*2*HID + w1off + h];
        w1c1[n] = W1[1*2*HID + w1off + h];
        w1c2[n] = W1[2*2*HID + w1off + h];
    }

    // each wave computes its 16 (m,r) partial triples once; wc==0 stores,
    // then wc==1 accumulates (rows are shared between the two column-waves)
    #pragma unroll
    for (int pass = 0; pass < 2; ++pass) {
        if (wc == pass) {
            #pragma unroll
            for (int m = 0; m < 4; ++m) {
                #pragma unroll
                for (int r = 0; r < 4; ++r) {
                    float p0 = 0.f, p1 = 0.f, p2 = 0.f;
                    #pragma unroll
                    for (int n = 0; n < 4; ++n) {
                        float s = fmaxf(acc[m][n][r] + bh[n], 0.f);
                        p0 = fmaf(s, w1c0[n], p0);
                        p1 = fmaf(s, w1c1[n], p1);
                        p2 = fmaf(s, w1c2[n], p2);
                    }
                    const int row = wr*64 + m*16 + l4*4 + r;
                    f32x4 v = (f32x4){p0, p1, p2, 0.f};
                    if (pass == 0) sm.red[row][l15] = v;
                    else           sm.red[row][l15] = sm.red[row][l15] + v;
                }
            }
        }
        __syncthreads();
    }

    // final: 2 threads per row sum 16 partial vectors, then 3 atomics/row
    {
        const int rrow = t >> 1, half = t & 1;
        f32x4 s = (f32x4){0.f, 0.f, 0.f, 0.f};
        #pragma unroll
        for (int j = 0; j < 8; ++j)
            s = s + sm.red[rrow][half*8 + ((j + rrow) & 7)];
        s.x += __shfl_xor(s.x, 1);
        s.y += __shfl_xor(s.y, 1);
        s.z += __shfl_xor(s.z, 1);
        if (half == 0) {
            const long grow = m0 + rrow;
            const float mk = msk[grow];
            atomicAdd(&proj[grow*3+0], s.x * mk);
            atomicAdd(&proj[grow*3+1], s.y * mk);
            atomicAdd(&proj[grow*3+2], s.z * mk);
        }
    }
#undef STAGE
}

// ---------------------------------------------------------------------------
// loss: 2048 blocks; block handles 4 consecutive d rows of one b (shared pe row)
// ---------------------------------------------------------------------------
__global__ __launch_bounds__(256)
void loss_kernel(const float* __restrict__ pe, const float* __restrict__ pd,
                 const float* __restrict__ b1, const int* __restrict__ labels,
                 float* __restrict__ psum, float* __restrict__ pcnt)
{
    const int g = blockIdx.x;            // 0..2047
    const int b = g >> 8;
    const int dbase = (g & 255) * 4;
    const int t = threadIdx.x;
    const int e0 = t * 4;

    const float4* pep = reinterpret_cast<const float4*>(pe + ((long)b*1024 + e0)*3);
    float4 q0 = pep[0], q1 = pep[1], q2 = pep[2];
    float epv[12] = {q0.x,q0.y,q0.z,q0.w, q1.x,q1.y,q1.z,q1.w, q2.x,q2.y,q2.z,q2.w};

    float lsum = 0.f, lcnt = 0.f;
    #pragma unroll
    for (int r = 0; r < 4; ++r) {
        const long bd = (long)b*1024 + dbase + r;
        const float d0 = pd[bd*3+0] + b1[0];
        const float d1 = pd[bd*3+1] + b1[1];
        const float d2 = pd[bd*3+2] + b1[2];
        const int4 lb = *reinterpret_cast<const int4*>(labels + bd*1024 + e0);
        const int lv[4] = {lb.x, lb.y, lb.z, lb.w};
        #pragma unroll
        for (int i = 0; i < 4; ++i) {
            float l0 = d0 + epv[i*3+0];
            float l1 = d1 + epv[i*3+1];
            float l2 = d2 + epv[i*3+2];
            float mx  = fmaxf(l0, fmaxf(l1, l2));
            float lse = mx + __logf(__expf(l0-mx) + __expf(l1-mx) + __expf(l2-mx));
            int la = lv[i];
            if (la != -100) {
                float sel = (la == 0) ? l0 : ((la == 1) ? l1 : l2);
                lsum += lse - sel;
                lcnt += 1.f;
            }
        }
    }
    #pragma unroll
    for (int off = 1; off < 64; off <<= 1) {
        lsum += __shfl_xor(lsum, off);
        lcnt += __shfl_xor(lcnt, off);
    }
    __shared__ float shs[4], shc[4];
    const int wv = t >> 6;
    if ((t & 63) == 0) { shs[wv] = lsum; shc[wv] = lcnt; }
    __syncthreads();
    if (t == 0) {
        psum[g] = shs[0]+shs[1]+shs[2]+shs[3];
        pcnt[g] = shc[0]+shc[1]+shc[2]+shc[3];
    }
}

__global__ __launch_bounds__(256)
void finalize_kernel(const float* __restrict__ psum, const float* __restrict__ pcnt,
                     float* __restrict__ out)
{
    const int t = threadIdx.x;
    float s = 0.f, c = 0.f;
    for (int i = t; i < 2048; i += 256) { s += psum[i]; c += pcnt[i]; }
    #pragma unroll
    for (int off = 1; off < 64; off <<= 1) {
        s += __shfl_xor(s, off);
        c += __shfl_xor(c, off);
    }
    __shared__ float shs[4], shc[4];
    const int wv = t >> 6;
    if ((t & 63) == 0) { shs[wv] = s; shc[wv] = c; }
    __syncthreads();
    if (t == 0)
        out[0] = (shs[0]+shs[1]+shs[2]+shs[3]) / fmaxf(shc[0]+shc[1]+shc[2]+shc[3], 1.0f);
}

// ---------------------------------------------------------------------------
extern "C" void kernel_launch(void* const* d_in, const int* in_sizes, int n_in,
                              void* d_out, int out_size, void* d_ws, size_t ws_size,
                              hipStream_t stream)
{
    (void)in_sizes; (void)n_in; (void)out_size; (void)ws_size;

    const float* enc   = (const float*)d_in[0];
    const float* dec   = (const float*)d_in[1];   // (1,B,D,F) -> base ptr
    const float* maske = (const float*)d_in[2];
    const float* maskd = (const float*)d_in[3];
    const float* We    = (const float*)d_in[4];
    const float* be    = (const float*)d_in[5];
    const float* Wd    = (const float*)d_in[6];
    const float* bd    = (const float*)d_in[7];
    const float* W1    = (const float*)d_in[8];
    const float* b1    = (const float*)d_in[9];
    const int*   labels= (const int*)d_in[10];

    float* pe   = (float*)d_ws;                   // 3*MR
    float* pd   = pe + 3*MR;                      // 3*MR
    float* psum = pd + 3*MR;                      // 2048
    float* pcnt = psum + MR;                      // 2048
    __bf16* Xeb = (__bf16*)(pcnt + MR);           // MR*FD
    __bf16* Xdb = Xeb + (long)MR*FD;              // MR*FD
    __bf16* Web = Xdb + (long)MR*FD;              // HID*FD
    __bf16* Wdb = Web + (long)HID*FD;             // HID*FD

    hipMemsetAsync(d_ws, 0, (size_t)(6*MR) * sizeof(float), stream);

    cvt_kernel<<<6912, 256, 0, stream>>>(enc, dec, We, Wd, Xeb, Xdb, Web, Wdb);

    dim3 grid(MR/BM, HID/BN, 2);
    gemm_proj_kernel<<<grid, 256, 0, stream>>>(Xeb, Xdb, Web, Wdb,
                                               maske, maskd, be, bd, W1, pe, pd);
    loss_kernel<<<2048, 256, 0, stream>>>(pe, pd, b1, labels, psum, pcnt);
    finalize_kernel<<<1, 256, 0, stream>>>(psum, pcnt, (float*)d_out);
}

// Round 9
// 180.249 us; speedup vs baseline: 2.5562x; 1.0132x over previous
//
#include <hip/hip_runtime.h>
#include <hip/hip_bf16.h>

typedef __attribute__((ext_vector_type(8))) __bf16 bf16x8;
typedef __attribute__((ext_vector_type(4))) float f32x4;

#define HID 1024      // H
#define FD  768       // F (K of first GEMM)
#define MR  8192      // B*E == B*D rows
#define BM  128
#define BN  128
#define BK  32
#define KSTEPS (FD / BK)   // 24

#define GLOAD_LDS16(g, l)                                                  \
    __builtin_amdgcn_global_load_lds(                                      \
        (const __attribute__((address_space(1))) unsigned int*)(g),        \
        (__attribute__((address_space(3))) unsigned int*)(l), 16, 0, 0)

// ---------------------------------------------------------------------------
// f32 -> bf16 conversion pass (Xe, Xd, We, Wd), 8 elems/thread
// ---------------------------------------------------------------------------
__global__ __launch_bounds__(256)
void cvt_kernel(const float* __restrict__ se, const float* __restrict__ sd,
                const float* __restrict__ swe, const float* __restrict__ swd,
                __bf16* __restrict__ de, __bf16* __restrict__ dd,
                __bf16* __restrict__ dwe, __bf16* __restrict__ dwd)
{
    const int blk = blockIdx.x;
    const float* __restrict__ src;
    __bf16* __restrict__ dst;
    long base;
    if (blk < 3072)      { src = se;  dst = de;  base = (long)blk * 2048; }
    else if (blk < 6144) { src = sd;  dst = dd;  base = (long)(blk - 3072) * 2048; }
    else if (blk < 6528) { src = swe; dst = dwe; base = (long)(blk - 6144) * 2048; }
    else                 { src = swd; dst = dwd; base = (long)(blk - 6528) * 2048; }
    const long i = base + (long)threadIdx.x * 8;
    const float4 a = *reinterpret_cast<const float4*>(src + i);
    const float4 b = *reinterpret_cast<const float4*>(src + i + 4);
    bf16x8 w;
    w[0] = (__bf16)a.x; w[1] = (__bf16)a.y; w[2] = (__bf16)a.z; w[3] = (__bf16)a.w;
    w[4] = (__bf16)b.x; w[5] = (__bf16)b.y; w[6] = (__bf16)b.z; w[7] = (__bf16)b.w;
    *reinterpret_cast<bf16x8*>(dst + i) = w;
}

// ---------------------------------------------------------------------------
// Fused: s = relu(Xb @ Wb^T + b) ; proj[row][c] += mask[row]*sum_h s*W1[c][w1off+h]
// T3-minimum pipeline: double-buffered LDS, prefetch STAGE before compute,
// ONE barrier per K-step. Epilogue: two-pass LDS reduction (union over staging).
// ---------------------------------------------------------------------------
__global__ __launch_bounds__(256)
void gemm_proj_kernel(const __bf16* __restrict__ Xe, const __bf16* __restrict__ Xd,
                      const __bf16* __restrict__ We, const __bf16* __restrict__ Wd,
                      const float* __restrict__ me, const float* __restrict__ md,
                      const float* __restrict__ be, const float* __restrict__ bd,
                      const float* __restrict__ W1,
                      float* __restrict__ pe, float* __restrict__ pd)
{
    const int z = blockIdx.z;
    const __bf16* __restrict__ X    = z ? Xd : Xe;
    const __bf16* __restrict__ Wt   = z ? Wd : We;
    const float* __restrict__ bias  = z ? bd : be;
    const float* __restrict__ msk   = z ? md : me;
    float* __restrict__ proj        = z ? pd : pe;
    const int w1off = z ? 0 : HID;

    __shared__ union {
        struct { __bf16 A[2][BM][BK]; __bf16 B[2][BN][BK]; } st;  // 32 KB
        f32x4 red[BM][16];                                        // 32 KB
    } sm;

    const int t    = threadIdx.x;
    const int lane = t & 63;
    const int wid  = t >> 6;
    const int wr   = wid >> 1;
    const int wc   = wid & 1;
    const int l15  = lane & 15;
    const int l4   = lane >> 4;

    const long m0 = (long)blockIdx.x * BM;
    const int  n0 = blockIdx.y * BN;

    f32x4 acc[4][4];
    #pragma unroll
    for (int i = 0; i < 4; ++i)
        #pragma unroll
        for (int j = 0; j < 4; ++j)
            acc[i][j] = (f32x4){0.f, 0.f, 0.f, 0.f};

    // staging geometry: wave wid stages rows [wid*32, wid*32+32) of A and B.
    // one issue covers 16 rows (1024 B linear); lane l -> row l>>2, 16B chunk l&3
    const int srow = lane >> 2;
    const int scol = (lane & 3) * 8;
    const __bf16* ga = X  + (m0 + wid*32 + srow) * (long)FD + scol;
    const __bf16* gb = Wt + (long)(n0 + wid*32 + srow) * FD + scol;

#define STAGE(p, ks) do {                                                  \
        const int k0_ = (ks) * BK;                                         \
        GLOAD_LDS16(ga + k0_,               &sm.st.A[p][wid*32 +  0][0]);  \
        GLOAD_LDS16(ga + (long)16*FD + k0_, &sm.st.A[p][wid*32 + 16][0]);  \
        GLOAD_LDS16(gb + k0_,               &sm.st.B[p][wid*32 +  0][0]);  \
        GLOAD_LDS16(gb + (long)16*FD + k0_, &sm.st.B[p][wid*32 + 16][0]);  \
    } while (0)

    STAGE(0, 0);
    __syncthreads();

    int cur = 0;
    for (int ks = 0; ks < KSTEPS; ++ks) {
        if (ks + 1 < KSTEPS) STAGE(cur ^ 1, ks + 1);   // prefetch next tile

        bf16x8 af[4], bfr[4];
        #pragma unroll
        for (int m = 0; m < 4; ++m)
            af[m] = *reinterpret_cast<const bf16x8*>(&sm.st.A[cur][wr*64 + m*16 + l15][l4*8]);
        #pragma unroll
        for (int n = 0; n < 4; ++n)
            bfr[n] = *reinterpret_cast<const bf16x8*>(&sm.st.B[cur][wc*64 + n*16 + l15][l4*8]);

        #pragma unroll
        for (int m = 0; m < 4; ++m)
            #pragma unroll
            for (int n = 0; n < 4; ++n)
                acc[m][n] = __builtin_amdgcn_mfma_f32_16x16x32_bf16(
                                af[m], bfr[n], acc[m][n], 0, 0, 0);

        __syncthreads();   // drains vmcnt (stage landed) + lgkm; buffers swap-safe
        cur ^= 1;
    }

    // ---- epilogue: bias+relu, dot 3 W1 rows, two-pass LDS accumulate ----
    float bh[4], w1c0[4], w1c1[4], w1c2[4];
    #pragma unroll
    for (int n = 0; n < 4; ++n) {
        int h = n0 + wc*64 + n*16 + l15;
        bh[n]   = bias[h];
        w1c0[n] = W1[0*2*HID + w1off + h];
        w1c1[n] = W1[1*2*HID + w1off + h];
        w1c2[n] = W1[2*2*HID + w1off + h];
    }

    // each wave computes its 16 (m,r) partial triples once; wc==0 stores,
    // then wc==1 accumulates (rows are shared between the two column-waves)
    #pragma unroll
    for (int pass = 0; pass < 2; ++pass) {
        if (wc == pass) {
            #pragma unroll
            for (int m = 0; m < 4; ++m) {
                #pragma unroll
                for (int r = 0; r < 4; ++r) {
                    float p0 = 0.f, p1 = 0.f, p2 = 0.f;
                    #pragma unroll
                    for (int n = 0; n < 4; ++n) {
                        float s = fmaxf(acc[m][n][r] + bh[n], 0.f);
                        p0 = fmaf(s, w1c0[n], p0);
                        p1 = fmaf(s, w1c1[n], p1);
                        p2 = fmaf(s, w1c2[n], p2);
                    }
                    const int row = wr*64 + m*16 + l4*4 + r;
                    f32x4 v = (f32x4){p0, p1, p2, 0.f};
                    if (pass == 0) sm.red[row][l15] = v;
                    else           sm.red[row][l15] = sm.red[row][l15] + v;
                }
            }
        }
        __syncthreads();
    }

    // final: 2 threads per row sum 16 partial vectors, then 3 atomics/row
    {
        const int rrow = t >> 1, half = t & 1;
        f32x4 s = (f32x4){0.f, 0.f, 0.f, 0.f};
        #pragma unroll
        for (int j = 0; j < 8; ++j)
            s = s + sm.red[rrow][half*8 + ((j + rrow) & 7)];
        s.x += __shfl_xor(s.x, 1);
        s.y += __shfl_xor(s.y, 1);
        s.z += __shfl_xor(s.z, 1);
        if (half == 0) {
            const long grow = m0 + rrow;
            const float mk = msk[grow];
            atomicAdd(&proj[grow*3+0], s.x * mk);
            atomicAdd(&proj[grow*3+1], s.y * mk);
            atomicAdd(&proj[grow*3+2], s.z * mk);
        }
    }
#undef STAGE
}

// ---------------------------------------------------------------------------
// loss: 2048 blocks; block handles 4 consecutive d rows of one b (shared pe row)
// ---------------------------------------------------------------------------
__global__ __launch_bounds__(256)
void loss_kernel(const float* __restrict__ pe, const float* __restrict__ pd,
                 const float* __restrict__ b1, const int* __restrict__ labels,
                 float* __restrict__ psum, float* __restrict__ pcnt)
{
    const int g = blockIdx.x;            // 0..2047
    const int b = g >> 8;
    const int dbase = (g & 255) * 4;
    const int t = threadIdx.x;
    const int e0 = t * 4;

    const float4* pep = reinterpret_cast<const float4*>(pe + ((long)b*1024 + e0)*3);
    float4 q0 = pep[0], q1 = pep[1], q2 = pep[2];
    float epv[12] = {q0.x,q0.y,q0.z,q0.w, q1.x,q1.y,q1.z,q1.w, q2.x,q2.y,q2.z,q2.w};

    float lsum = 0.f, lcnt = 0.f;
    #pragma unroll
    for (int r = 0; r < 4; ++r) {
        const long bd = (long)b*1024 + dbase + r;
        const float d0 = pd[bd*3+0] + b1[0];
        const float d1 = pd[bd*3+1] + b1[1];
        const float d2 = pd[bd*3+2] + b1[2];
        const int4 lb = *reinterpret_cast<const int4*>(labels + bd*1024 + e0);
        const int lv[4] = {lb.x, lb.y, lb.z, lb.w};
        #pragma unroll
        for (int i = 0; i < 4; ++i) {
            float l0 = d0 + epv[i*3+0];
            float l1 = d1 + epv[i*3+1];
            float l2 = d2 + epv[i*3+2];
            float mx  = fmaxf(l0, fmaxf(l1, l2));
            float lse = mx + __logf(__expf(l0-mx) + __expf(l1-mx) + __expf(l2-mx));
            int la = lv[i];
            if (la != -100) {
                float sel = (la == 0) ? l0 : ((la == 1) ? l1 : l2);
                lsum += lse - sel;
                lcnt += 1.f;
            }
        }
    }
    #pragma unroll
    for (int off = 1; off < 64; off <<= 1) {
        lsum += __shfl_xor(lsum, off);
        lcnt += __shfl_xor(lcnt, off);
    }
    __shared__ float shs[4], shc[4];
    const int wv = t >> 6;
    if ((t & 63) == 0) { shs[wv] = lsum; shc[wv] = lcnt; }
    __syncthreads();
    if (t == 0) {
        psum[g] = shs[0]+shs[1]+shs[2]+shs[3];
        pcnt[g] = shc[0]+shc[1]+shc[2]+shc[3];
    }
}

__global__ __launch_bounds__(256)
void finalize_kernel(const float* __restrict__ psum, const float* __restrict__ pcnt,
                     float* __restrict__ out)
{
    const int t = threadIdx.x;
    float s = 0.f, c = 0.f;
    for (int i = t; i < 2048; i += 256) { s += psum[i]; c += pcnt[i]; }
    #pragma unroll
    for (int off = 1; off < 64; off <<= 1) {
        s += __shfl_xor(s, off);
        c += __shfl_xor(c, off);
    }
    __shared__ float shs[4], shc[4];
    const int wv = t >> 6;
    if ((t & 63) == 0) { shs[wv] = s; shc[wv] = c; }
    __syncthreads();
    if (t == 0)
        out[0] = (shs[0]+shs[1]+shs[2]+shs[3]) / fmaxf(shc[0]+shc[1]+shc[2]+shc[3], 1.0f);
}

// ---------------------------------------------------------------------------
extern "C" void kernel_launch(void* const* d_in, const int* in_sizes, int n_in,
                              void* d_out, int out_size, void* d_ws, size_t ws_size,
                              hipStream_t stream)
{
    (void)in_sizes; (void)n_in; (void)out_size; (void)ws_size;

    const float* enc   = (const float*)d_in[0];
    const float* dec   = (const float*)d_in[1];   // (1,B,D,F) -> base ptr
    const float* maske = (const float*)d_in[2];
    const float* maskd = (const float*)d_in[3];
    const float* We    = (const float*)d_in[4];
    const float* be    = (const float*)d_in[5];
    const float* Wd    = (const float*)d_in[6];
    const float* bd    = (const float*)d_in[7];
    const float* W1    = (const float*)d_in[8];
    const float* b1    = (const float*)d_in[9];
    const int*   labels= (const int*)d_in[10];

    float* pe   = (float*)d_ws;                   // 3*MR
    float* pd   = pe + 3*MR;                      // 3*MR
    float* psum = pd + 3*MR;                      // 2048
    float* pcnt = psum + MR;                      // 2048
    __bf16* Xeb = (__bf16*)(pcnt + MR);           // MR*FD
    __bf16* Xdb = Xeb + (long)MR*FD;              // MR*FD
    __bf16* Web = Xdb + (long)MR*FD;              // HID*FD
    __bf16* Wdb = Web + (long)HID*FD;             // HID*FD

    hipMemsetAsync(d_ws, 0, (size_t)(6*MR) * sizeof(float), stream);

    cvt_kernel<<<6912, 256, 0, stream>>>(enc, dec, We, Wd, Xeb, Xdb, Web, Wdb);

    dim3 grid(MR/BM, HID/BN, 2);
    gemm_proj_kernel<<<grid, 256, 0, stream>>>(Xeb, Xdb, Web, Wdb,
                                               maske, maskd, be, bd, W1, pe, pd);
    loss_kernel<<<2048, 256, 0, stream>>>(pe, pd, b1, labels, psum, pcnt);
    finalize_kernel<<<1, 256, 0, stream>>>(psum, pcnt, (float*)d_out);
}